// Round 2
// baseline (212.863 us; speedup 1.0000x reference)
//
#include <hip/hip_runtime.h>

// ScaleDotProductAttention: B=2,H=16,S=2048,D=64 (fp32 in/out; bf16-adaptive).
// R9: latency-hiding pass on R8 (which cut VALU but exposed L2 latency).
//  - attn_fast: fully-unrolled 16-tile loop with explicit software pipeline:
//    next-tile K frags + current-tile V frags + next-it bits issued BEFORE the
//    QK MFMA chain, so ~300cy of MFMA+exp+pack hides the L2 latency.
//  - prep_all seg0 (mask->bits): 8 elements/thread (32768 -> 4096 blocks).

#define S_LEN 2048
#define D_DIM 64
#define WPR   32
#define NIT   32

typedef __attribute__((ext_vector_type(8)))  short bf16x8;
typedef __attribute__((ext_vector_type(4)))  float f32x4;
typedef __attribute__((ext_vector_type(16))) float f32x16;
typedef unsigned uint2v __attribute__((ext_vector_type(2)));
typedef unsigned long long ull;

__device__ __forceinline__ f32x16 mfma32(bf16x8 a, bf16x8 b, f32x16 c) {
  return __builtin_amdgcn_mfma_f32_32x32x16_bf16(a, b, c, 0, 0, 0);
}
__device__ __forceinline__ f32x4 mfma16(bf16x8 a, bf16x8 b, f32x4 c) {
  return __builtin_amdgcn_mfma_f32_16x16x32_bf16(a, b, c, 0, 0, 0);
}
__device__ __forceinline__ unsigned short f2bf(float f) {
  unsigned u = __builtin_bit_cast(unsigned, f);
  unsigned r = u + 0x7FFFu + ((u >> 16) & 1u);
  return (unsigned short)(r >> 16);
}
__device__ __forceinline__ float bf2f(unsigned short s) {
  unsigned u = ((unsigned)s) << 16;
  return __builtin_bit_cast(float, u);
}
__device__ __forceinline__ unsigned packbf(float a, float b) {
  // gfx950: v_cvt_pk_bf16_f32 (RNE), no clang builtin -> inline asm (T12).
  unsigned r;
  asm("v_cvt_pk_bf16_f32 %0, %1, %2" : "=v"(r) : "v"(a), "v"(b));
  return r;
}
__device__ __forceinline__ float fexp2(float x) {
#if __has_builtin(__builtin_amdgcn_exp2f)
  return __builtin_amdgcn_exp2f(x);
#else
  return exp2f(x);
#endif
}
__device__ __forceinline__ bool detect_bf16(const void* maskp) {
  const unsigned short* s = (const unsigned short*)maskp;
  unsigned short v = s[2 * (threadIdx.x & 63)];
  return __ballot(v == (unsigned short)0x3F80) != 0ull;
}
__device__ __forceinline__ int4 cvt_f8(const float* p) {
  float4 f0 = *(const float4*)p;
  float4 f1 = *(const float4*)(p + 4);
  int4 r;
  r.x = (int)packbf(f0.x, f0.y);
  r.y = (int)packbf(f0.z, f0.w);
  r.z = (int)packbf(f1.x, f1.y);
  r.w = (int)packbf(f1.z, f1.w);
  return r;
}

#define C1 0.18033688011112042f     /* (1/sqrt(64))*log2(e) */
#define C2 1.4426950408889634e9f

#define SEG0 4096u
#define SEG1 2048u
#define SEG2 1024u
#define SEG3 2048u

// ---------------- unified prepass ----------------
// seg0 (4096):  mask -> bits (8 elems/thread), transposed: bits[((b*32+word)<<11)+row]
// seg1 (2048):  K -> Kf 32x32 A-frags (R6-verified layout)
// seg2 (1024):  V -> Vf 32x32 B-frags (R6-verified layout)
// seg3 (2048):  Q -> Qc bf16 row-major, pre-scaled by C1
__global__ __launch_bounds__(256) void prep_all(
    const void* __restrict__ M, const void* __restrict__ Kin,
    const void* __restrict__ Vin, const void* __restrict__ Qin,
    ull* __restrict__ bits, unsigned short* __restrict__ Kf,
    unsigned short* __restrict__ Vf, unsigned short* __restrict__ Qc) {
  __shared__ __align__(16) unsigned short T[64 * 72];
  const bool isb = detect_bf16(M);
  const unsigned bx = blockIdx.x;
  const int tid = threadIdx.x;

  if (bx < SEG0) {            // ---- mask bits, 8 elements per thread
    unsigned e0 = bx * 2048u + tid;
    #pragma unroll
    for (int j = 0; j < 8; ++j) {
      unsigned idx = e0 + (unsigned)j * 256u;
      bool on = isb ? (bf2f(((const unsigned short*)M)[idx]) > 0.5f)
                    : (((const float*)M)[idx] > 0.5f);
      ull bm = __ballot(on);
      if ((tid & 63) == 0) {
        unsigned c = idx & 2047u, r = (idx >> 11) & 2047u, bb = idx >> 22;
        bits[(((size_t)(bb * WPR + (c >> 6))) << 11) + r] = bm;
      }
    }
  } else if (bx < SEG0 + SEG1) {   // ---- Kf gather
    unsigned g = (bx - SEG0) * 256u + tid;
    unsigned lane = g & 63u, f = (g >> 6) & 7u, it = (g >> 9) & 31u, bh = g >> 14;
    unsigned t = f >> 2, dc = f & 3, hi = lane >> 5, l31 = lane & 31;
    size_t src = (size_t)bh * (S_LEN * D_DIM) +
                 (size_t)(it * 64 + t * 32 + l31) * D_DIM + dc * 16 + hi * 8;
    int4 out;
    if (isb) out = *(const int4*)((const unsigned short*)Kin + src);
    else     out = cvt_f8((const float*)Kin + src);
    *(int4*)&Kf[(size_t)g * 8] = out;
  } else if (bx < SEG0 + SEG1 + SEG2) {  // ---- Vf transpose via LDS
    unsigned idx = bx - (SEG0 + SEG1);
    unsigned bh = idx >> 5, it = idx & 31u;
    {
      int k = tid >> 2, d0 = (tid & 3) * 16;
      size_t src = (size_t)bh * (S_LEN * D_DIM) + (size_t)(it * 64 + k) * D_DIM + d0;
      int4 a, c;
      if (isb) {
        const unsigned short* s = (const unsigned short*)Vin + src;
        a = *(const int4*)s; c = *(const int4*)(s + 8);
      } else {
        const float* s = (const float*)Vin + src;
        a = cvt_f8(s); c = cvt_f8(s + 8);
      }
      *(int4*)&T[k * 72 + d0] = a;
      *(int4*)&T[k * 72 + d0 + 8] = c;
    }
    __syncthreads();
    #pragma unroll
    for (int h = 0; h < 2; ++h) {
      int c = tid + h * 256;
      int lane = c & 63, f = c >> 6;
      int t = f >> 2, kc = (f >> 1) & 1, dt = f & 1;
      int hi = lane >> 5, l31 = lane & 31;
      unsigned short v[8];
      #pragma unroll
      for (int j = 0; j < 8; ++j)
        v[j] = T[(t * 32 + kc * 16 + hi * 8 + j) * 72 + dt * 32 + l31];
      *(int4*)&Vf[(((size_t)(bh * 32 + it)) * 8 + f) * 512 + lane * 8] = *(int4*)v;
    }
  } else {                       // ---- Qc: row-major bf16, scaled by C1
    size_t i0 = ((size_t)(bx - (SEG0 + SEG1 + SEG2)) * 256 + tid) * 8;
    unsigned short v[8];
    if (isb) {
      *(int4*)v = *(const int4*)((const unsigned short*)Qin + i0);
      #pragma unroll
      for (int j = 0; j < 8; ++j) v[j] = f2bf(bf2f(v[j]) * C1);
    } else {
      const float* f = (const float*)Qin + i0;
      #pragma unroll
      for (int j = 0; j < 4; ++j)
        *((unsigned*)v + j) = packbf(f[2 * j] * C1, f[2 * j + 1] * C1);
    }
    *(int4*)&Qc[i0] = *(int4*)v;
  }
}

// ---------------- barrier-free 32x32 attention, XCD-affine, pipelined ----------------
// flat grid 2048; id -> xcd=id&7, bh=xcd*4+(slot&3), qt=slot>>2.
__global__ __launch_bounds__(256, 4) void attn_fast(
    const unsigned short* __restrict__ Qc, const unsigned short* __restrict__ Kf,
    const unsigned short* __restrict__ Vf, const ull* __restrict__ bits,
    const void* __restrict__ maskp, void* __restrict__ Op) {
  __shared__ float Comb[2][32][64];   // staged O-combine (16 KB)
  __shared__ float Lc[4][32];         // per-wave row-sums

  const bool isb = detect_bf16(maskp);
  const int tid  = threadIdx.x;
  const int wave = tid >> 6;
  const int lane = tid & 63;
  const int hi   = lane >> 5;
  const int l31  = lane & 31;
  const int id   = blockIdx.x;
  const int slot = id >> 3;
  const int bh   = (id & 7) * 4 + (slot & 3);   // XCD-affine: 4 bh per XCD
  const int q0   = (slot >> 2) * 32;
  const int b    = bh >> 4;
  const size_t base = (size_t)bh * S_LEN * D_DIM;
  const int xidx = ((lane ^ 32) & 63) * 4;      // ds_bpermute byte index

  // Q B-fragments: bf16 row-major, already scaled
  bf16x8 qf[4];
  #pragma unroll
  for (int dc = 0; dc < 4; ++dc)
    qf[dc] = *(const bf16x8*)&Qc[base + (size_t)(q0 + l31) * D_DIM + dc * 16 + hi * 8];

  // Per-wave fragment bases: frag (i*8 + t*4 + dc) lives at offset*512.
  const unsigned short* KbBase = Kf + ((size_t)(bh * 32 + wave * 8) * 8) * 512 + lane * 8;
  const unsigned short* VbBase = Vf + ((size_t)(bh * 32 + wave * 8) * 8) * 512 + lane * 8;
  const size_t bitrow = ((size_t)(b * WPR + wave * 8) << 11) + q0 + l31;

  f32x16 acc_o[2];   // [dt]: O[m=(reg&3)+8(reg>>2)+4hi][d=dt*32+l31]
  float ls0 = 0.f, ls1 = 0.f, ls2 = 0.f, ls3 = 0.f;  // partial row-sums
  #pragma unroll
  for (int r = 0; r < 16; ++r) { acc_o[0][r] = 0.f; acc_o[1][r] = 0.f; }

  // Prime the pipeline: K frags of tile 0 and bits of it=wave*8.
  bf16x8 ka[4];
  #pragma unroll
  for (int dc = 0; dc < 4; ++dc)
    ka[dc] = *(const bf16x8*)(KbBase + (size_t)dc * 512);
  ull wcur = bits[bitrow];

  #pragma unroll
  for (int tt = 0; tt < 16; ++tt) {
    const int i = tt >> 1, t = tt & 1;
    const int off = i * 8 + t * 4;

    // --- issue next-tile K loads (consumed next iteration) ---
    bf16x8 kn[4];
    if (tt < 15) {
      #pragma unroll
      for (int dc = 0; dc < 4; ++dc)
        kn[dc] = *(const bf16x8*)(KbBase + (size_t)(off + 4 + dc) * 512);
    }
    // --- issue next-it bits load (consumed in 2 tiles) ---
    ull wnext = wcur;
    if (t == 1 && i < 7) wnext = bits[bitrow + ((size_t)(i + 1) << 11)];
    // --- issue current-tile V loads (consumed after exp/pack) ---
    bf16x8 vv[4];   // [kc*2+dt]
    #pragma unroll
    for (int f = 0; f < 4; ++f)
      vv[f] = *(const bf16x8*)(VbBase + (size_t)(off + f) * 512);

    // --- QK^T on the pre-loaded ka ---
    f32x16 sc;
    #pragma unroll
    for (int r = 0; r < 16; ++r) sc[r] = 0.f;
    #pragma unroll
    for (int dc = 0; dc < 4; ++dc) sc = mfma32(ka[dc], qf[dc], sc);

    const unsigned wtv = (unsigned)((wcur >> (hi * 4)) >> (32 * t));

    float p[16];
    #pragma unroll
    for (int r = 0; r < 16; ++r) {
      float e = fexp2(sc[r]);
      unsigned bit = (wtv >> ((r & 3) + 8 * (r >> 2))) & 1u;
      p[r] = bit ? 0.0f : e;
    }
    // 4 partial sums: depth-4 dependency chain instead of 16
    ls0 += p[0] + p[4] + p[8]  + p[12];
    ls1 += p[1] + p[5] + p[9]  + p[13];
    ls2 += p[2] + p[6] + p[10] + p[14];
    ls3 += p[3] + p[7] + p[11] + p[15];

    #pragma unroll
    for (int kc = 0; kc < 2; ++kc) {
      unsigned pk0 = packbf(p[8 * kc + 0], p[8 * kc + 1]);
      unsigned pk1 = packbf(p[8 * kc + 2], p[8 * kc + 3]);
      unsigned pk2 = packbf(p[8 * kc + 4], p[8 * kc + 5]);
      unsigned pk3 = packbf(p[8 * kc + 6], p[8 * kc + 7]);
      uint4 d;
#if __has_builtin(__builtin_amdgcn_permlane32_swap)
      uint2v s02 = __builtin_amdgcn_permlane32_swap(pk0, pk2, false, false);
      uint2v s13 = __builtin_amdgcn_permlane32_swap(pk1, pk3, false, false);
      d.x = s02[0]; d.z = s02[1];
      d.y = s13[0]; d.w = s13[1];
#else
      unsigned x0 = (unsigned)__builtin_amdgcn_ds_bpermute(xidx, (int)pk0);
      unsigned x1 = (unsigned)__builtin_amdgcn_ds_bpermute(xidx, (int)pk1);
      unsigned x2 = (unsigned)__builtin_amdgcn_ds_bpermute(xidx, (int)pk2);
      unsigned x3 = (unsigned)__builtin_amdgcn_ds_bpermute(xidx, (int)pk3);
      d.x = hi ? x2 : pk0;
      d.y = hi ? x3 : pk1;
      d.z = hi ? pk2 : x0;
      d.w = hi ? pk3 : x1;
#endif
      bf16x8 pf = __builtin_bit_cast(bf16x8, d);
      #pragma unroll
      for (int dt = 0; dt < 2; ++dt)
        acc_o[dt] = mfma32(pf, vv[kc * 2 + dt], acc_o[dt]);
    }

    // --- rotate pipeline registers (coalesced away by full unroll) ---
    if (tt < 15) {
      #pragma unroll
      for (int dc = 0; dc < 4; ++dc) ka[dc] = kn[dc];
    }
    if (t == 1) wcur = wnext;
  }

  float lsum = (ls0 + ls1) + (ls2 + ls3);
  // complete this wave's row-sum: add partner hi-half
  {
    int li = __builtin_bit_cast(int, lsum);
    float other = __builtin_bit_cast(float, __builtin_amdgcn_ds_bpermute(xidx, li));
    lsum += other;
  }

  // ---- staged combine of the 4 iteration quarters (fixed max -> pure add)
  __syncthreads();
  if (wave >= 2) {
    #pragma unroll
    for (int dt = 0; dt < 2; ++dt)
      #pragma unroll
      for (int r = 0; r < 16; ++r)
        Comb[wave - 2][dt * 16 + r][lane] = acc_o[dt][r];
  }
  if (hi == 0) Lc[wave][l31] = lsum;
  __syncthreads();
  if (wave < 2) {
    #pragma unroll
    for (int dt = 0; dt < 2; ++dt)
      #pragma unroll
      for (int r = 0; r < 16; ++r)
        acc_o[dt][r] += Comb[wave][dt * 16 + r][lane];
  }
  __syncthreads();
  if (wave == 1) {
    #pragma unroll
    for (int dt = 0; dt < 2; ++dt)
      #pragma unroll
      for (int r = 0; r < 16; ++r)
        Comb[0][dt * 16 + r][lane] = acc_o[dt][r];
  }
  __syncthreads();
  if (wave == 0) {
    #pragma unroll
    for (int r = 0; r < 16; ++r) {
      int m = (r & 3) + 8 * (r >> 2) + 4 * hi;
      float o0 = acc_o[0][r] + Comb[0][r][lane];
      float o1 = acc_o[1][r] + Comb[0][16 + r][lane];
      float lv = Lc[0][m] + Lc[1][m] + Lc[2][m] + Lc[3][m];
      float inv = 1.0f / lv;
      size_t idx = base + (size_t)(q0 + m) * D_DIM + l31;
      if (isb) {
        ((unsigned short*)Op)[idx]      = f2bf(o0 * inv);
        ((unsigned short*)Op)[idx + 32] = f2bf(o1 * inv);
      } else {
        ((float*)Op)[idx]      = o0 * inv;
        ((float*)Op)[idx + 32] = o1 * inv;
      }
    }
  }
}

// ---------------- no-workspace fallback (R2-proven structure) ----------------
__global__ __launch_bounds__(256, 2) void attn_fallback(
    const void* __restrict__ Qp, const void* __restrict__ Kp,
    const void* __restrict__ Vp, const void* __restrict__ maskp,
    void* __restrict__ Op) {
  __shared__ __align__(16) short QKlds[128 * 72];
  __shared__ __align__(16) short Vtlds[64 * 72];
  __shared__ __align__(16) short Plds2[128 * 72];

  const bool isb = detect_bf16(maskp);
  const int tid  = threadIdx.x;
  const int wave = tid >> 6;
  const int lane = tid & 63;
  const int l15  = lane & 15;
  const int quad = lane >> 4;
  const int q0   = blockIdx.x * 128;
  const int bh   = blockIdx.y;
  const int b    = bh >> 4;
  const size_t base = (size_t)bh * S_LEN * D_DIM;

  const short* Qs = (const short*)Qp; const float* Qf = (const float*)Qp;
  const short* Ks = (const short*)Kp; const float* Kf2 = (const float*)Kp;
  const short* Vs = (const short*)Vp; const float* Vf2 = (const float*)Vp;

  if (isb) {
    const short* Qg = Qs + base + (size_t)q0 * D_DIM;
    #pragma unroll
    for (int p = 0; p < 4; ++p) {
      int e = p * 2048 + tid * 8;
      *(int4*)&QKlds[(e >> 6) * 72 + (e & 63)] = *(const int4*)(Qg + e);
    }
  } else {
    const float* Qg = Qf + base + (size_t)q0 * D_DIM;
    #pragma unroll
    for (int p = 0; p < 4; ++p) {
      int e = p * 2048 + tid * 8;
      *(int4*)&QKlds[(e >> 6) * 72 + (e & 63)] = cvt_f8(Qg + e);
    }
  }
  __syncthreads();
  bf16x8 qf[2][2];
  #pragma unroll
  for (int mi = 0; mi < 2; ++mi)
    #pragma unroll
    for (int kt = 0; kt < 2; ++kt)
      qf[mi][kt] = *(const bf16x8*)&QKlds[(wave * 32 + mi * 16 + l15) * 72 + kt * 32 + quad * 8];
  __syncthreads();

  f32x4 acc_o[2][4];
  f32x4 acc_l[2];
  const f32x4 zero4 = {0.f, 0.f, 0.f, 0.f};
  #pragma unroll
  for (int mi = 0; mi < 2; ++mi) {
    acc_l[mi] = zero4;
    #pragma unroll
    for (int nt = 0; nt < 4; ++nt) acc_o[mi][nt] = zero4;
  }
  bf16x8 onesB;
  {
    short ov = (l15 == 0) ? (short)0x3F80 : (short)0;
    #pragma unroll
    for (int i = 0; i < 8; ++i) onesB[i] = ov;
  }

  for (int it = 0; it < NIT; ++it) {
    const int k0 = it * 64;
    if (isb) {
      const short* Kg = Ks + base + (size_t)k0 * D_DIM;
      #pragma unroll
      for (int p = 0; p < 2; ++p) {
        int e = p * 2048 + tid * 8;
        *(int4*)&QKlds[(e >> 6) * 72 + (e & 63)] = *(const int4*)(Kg + e);
      }
    } else {
      const float* Kg = Kf2 + base + (size_t)k0 * D_DIM;
      #pragma unroll
      for (int p = 0; p < 2; ++p) {
        int e = p * 2048 + tid * 8;
        *(int4*)&QKlds[(e >> 6) * 72 + (e & 63)] = cvt_f8(Kg + e);
      }
    }
    {
      const int r0 = (tid >> 3) * 2;
      const int d0 = (tid & 7) * 8;
      unsigned short as_[8], bs_[8];
      if (isb) {
        const short* Vg = Vs + base + (size_t)k0 * D_DIM;
        *(int4*)as_ = *(const int4*)(Vg + r0 * D_DIM + d0);
        *(int4*)bs_ = *(const int4*)(Vg + (r0 + 1) * D_DIM + d0);
      } else {
        const float* Vg = Vf2 + base + (size_t)k0 * D_DIM;
        *(int4*)as_ = cvt_f8(Vg + r0 * D_DIM + d0);
        *(int4*)bs_ = cvt_f8(Vg + (r0 + 1) * D_DIM + d0);
      }
      #pragma unroll
      for (int j = 0; j < 8; ++j) {
        int d = d0 + j;
        int blk = (r0 >> 3) ^ (d >> 3);
        unsigned pk = (unsigned)as_[j] | ((unsigned)bs_[j] << 16);
        *(unsigned*)&Vtlds[d * 72 + blk * 8 + (r0 & 7)] = pk;
      }
    }
    __syncthreads();

    f32x4 sc[2][4];
    #pragma unroll
    for (int mi = 0; mi < 2; ++mi)
      #pragma unroll
      for (int nt = 0; nt < 4; ++nt) sc[mi][nt] = zero4;
    #pragma unroll
    for (int nt = 0; nt < 4; ++nt) {
      bf16x8 kf0 = *(const bf16x8*)&QKlds[(nt * 16 + l15) * 72 + quad * 8];
      bf16x8 kf1 = *(const bf16x8*)&QKlds[(nt * 16 + l15) * 72 + 32 + quad * 8];
      #pragma unroll
      for (int mi = 0; mi < 2; ++mi) {
        sc[mi][nt] = mfma16(qf[mi][0], kf0, sc[mi][nt]);
        sc[mi][nt] = mfma16(qf[mi][1], kf1, sc[mi][nt]);
      }
    }

    #pragma unroll
    for (int mi = 0; mi < 2; ++mi) {
      #pragma unroll
      for (int nt = 0; nt < 4; ++nt) {
        #pragma unroll
        for (int reg = 0; reg < 4; ++reg) {
          int rg = q0 + wave * 32 + mi * 16 + quad * 4 + reg;
          size_t mix = (size_t)b * S_LEN * S_LEN + (size_t)rg * S_LEN + k0 + nt * 16 + l15;
          float mv = isb ? bf2f(((const unsigned short*)maskp)[mix])
                         : ((const float*)maskp)[mix];
          float y = sc[mi][nt][reg] * C1 - mv * C2;
          Plds2[(wave * 32 + mi * 16 + quad * 4 + reg) * 72 + nt * 16 + l15] =
              (short)f2bf(fexp2(y));
        }
      }
    }
    __syncthreads();

    #pragma unroll
    for (int kt = 0; kt < 2; ++kt) {
      bf16x8 pf[2];
      #pragma unroll
      for (int mi = 0; mi < 2; ++mi)
        pf[mi] = *(const bf16x8*)&Plds2[(wave * 32 + mi * 16 + l15) * 72 + kt * 32 + quad * 8];
      #pragma unroll
      for (int nt = 0; nt < 4; ++nt) {
        int d = nt * 16 + l15;
        int kb = (kt * 4 + quad) ^ (d >> 3);
        bf16x8 vf = *(const bf16x8*)&Vtlds[d * 72 + kb * 8];
        #pragma unroll
        for (int mi = 0; mi < 2; ++mi)
          acc_o[mi][nt] = mfma16(pf[mi], vf, acc_o[mi][nt]);
      }
      #pragma unroll
      for (int mi = 0; mi < 2; ++mi)
        acc_l[mi] = mfma16(pf[mi], onesB, acc_l[mi]);
    }
    __syncthreads();
  }

  #pragma unroll
  for (int mi = 0; mi < 2; ++mi) {
    #pragma unroll
    for (int reg = 0; reg < 4; ++reg) {
      float lv = __shfl(acc_l[mi][reg], lane & 48, 64);
      float inv = 1.0f / lv;
      #pragma unroll
      for (int nt = 0; nt < 4; ++nt) {
        float o = acc_o[mi][nt][reg] * inv;
        size_t idx = base + (size_t)(q0 + wave * 32 + mi * 16 + quad * 4 + reg) * D_DIM + nt * 16 + l15;
        if (isb) ((unsigned short*)Op)[idx] = f2bf(o);
        else     ((float*)Op)[idx] = o;
      }
    }
  }
}

extern "C" void kernel_launch(void* const* d_in, const int* in_sizes, int n_in,
                              void* d_out, int out_size, void* d_ws, size_t ws_size,
                              hipStream_t stream) {
  const void* Q = d_in[0];
  const void* K = d_in[1];
  const void* V = d_in[2];
  const void* M = d_in[3];

  dim3 block(256);
  const size_t bits_bytes = (size_t)2 * S_LEN * S_LEN / 8;          // 1 MB
  const size_t tens_bytes = (size_t)2 * 16 * S_LEN * D_DIM * 2;     // 8.4 MB bf16

  if (ws_size >= bits_bytes + 3 * tens_bytes) {
    char* ws = (char*)d_ws;
    ull* bits = (ull*)ws;
    unsigned short* Kf = (unsigned short*)(ws + bits_bytes);
    unsigned short* Vf = (unsigned short*)(ws + bits_bytes + tens_bytes);
    unsigned short* Qc = (unsigned short*)(ws + bits_bytes + 2 * tens_bytes);
    prep_all<<<dim3(SEG0 + SEG1 + SEG2 + SEG3), block, 0, stream>>>(
        M, K, V, Q, bits, Kf, Vf, Qc);
    attn_fast<<<dim3(2048), block, 0, stream>>>(Qc, Kf, Vf, bits, M, d_out);
  } else {
    attn_fallback<<<dim3(S_LEN / 128, 32), block, 0, stream>>>(Q, K, V, M, d_out);
  }
}

// Round 3
// 172.550 us; speedup vs baseline: 1.2336x; 1.2336x over previous
//
#include <hip/hip_runtime.h>

// ScaleDotProductAttention: B=2,H=16,S=2048,D=64 (fp32 in/out; bf16-adaptive).
// R10: LDS-staged restructure. R9 post-mortem: full-unroll reg pipeline caused
// load rematerialization (FETCH x3, 101us). Root cause across R7-R9: per-wave
// private K/V L2 reads (128KB/wave) are latency-bound. New mapping: block =
// 128 q-rows (4 waves x 32), all waves sweep the SAME k-subtile; K/V frags
// staged once per block into LDS via global_load_lds (linear frag layout ->
// wave-uniform dest OK, ds_read_b128 conflict-free), double-buffered, one
// __syncthreads per subtile. O-combine phase eliminated (waves own rows).

#define S_LEN 2048
#define D_DIM 64
#define WPR   32
#define NIT   32

typedef __attribute__((ext_vector_type(8)))  short bf16x8;
typedef __attribute__((ext_vector_type(4)))  float f32x4;
typedef __attribute__((ext_vector_type(16))) float f32x16;
typedef unsigned uint2v __attribute__((ext_vector_type(2)));
typedef unsigned long long ull;

__device__ __forceinline__ f32x16 mfma32(bf16x8 a, bf16x8 b, f32x16 c) {
  return __builtin_amdgcn_mfma_f32_32x32x16_bf16(a, b, c, 0, 0, 0);
}
__device__ __forceinline__ f32x4 mfma16(bf16x8 a, bf16x8 b, f32x4 c) {
  return __builtin_amdgcn_mfma_f32_16x16x32_bf16(a, b, c, 0, 0, 0);
}
__device__ __forceinline__ unsigned short f2bf(float f) {
  unsigned u = __builtin_bit_cast(unsigned, f);
  unsigned r = u + 0x7FFFu + ((u >> 16) & 1u);
  return (unsigned short)(r >> 16);
}
__device__ __forceinline__ float bf2f(unsigned short s) {
  unsigned u = ((unsigned)s) << 16;
  return __builtin_bit_cast(float, u);
}
__device__ __forceinline__ unsigned packbf(float a, float b) {
  // gfx950: v_cvt_pk_bf16_f32 (RNE), no clang builtin -> inline asm (T12).
  unsigned r;
  asm("v_cvt_pk_bf16_f32 %0, %1, %2" : "=v"(r) : "v"(a), "v"(b));
  return r;
}
__device__ __forceinline__ float fexp2(float x) {
#if __has_builtin(__builtin_amdgcn_exp2f)
  return __builtin_amdgcn_exp2f(x);
#else
  return exp2f(x);
#endif
}
__device__ __forceinline__ bool detect_bf16(const void* maskp) {
  const unsigned short* s = (const unsigned short*)maskp;
  unsigned short v = s[2 * (threadIdx.x & 63)];
  return __ballot(v == (unsigned short)0x3F80) != 0ull;
}
__device__ __forceinline__ int4 cvt_f8(const float* p) {
  float4 f0 = *(const float4*)p;
  float4 f1 = *(const float4*)(p + 4);
  int4 r;
  r.x = (int)packbf(f0.x, f0.y);
  r.y = (int)packbf(f0.z, f0.w);
  r.z = (int)packbf(f1.x, f1.y);
  r.w = (int)packbf(f1.z, f1.w);
  return r;
}
// Async 16B/lane global->LDS. g is PER-LANE src (base + lane*16B); l is the
// wave-uniform LDS base (HW writes lane i at l + i*16).
__device__ __forceinline__ void gl_lds16(const unsigned short* g, unsigned short* l) {
#if __has_builtin(__builtin_amdgcn_global_load_lds)
  __builtin_amdgcn_global_load_lds(
      (const __attribute__((address_space(1))) unsigned int*)g,
      (__attribute__((address_space(3))) unsigned int*)l, 16, 0, 0);
#else
  *(int4*)((char*)l + (threadIdx.x & 63) * 16) = *(const int4*)g;
#endif
}

#define C1 0.18033688011112042f     /* (1/sqrt(64))*log2(e) */
#define C2 1.4426950408889634e9f

#define SEG0 4096u
#define SEG1 2048u
#define SEG2 1024u
#define SEG3 2048u

// ---------------- unified prepass ----------------
// seg0 (4096):  mask -> bits (8 elems/thread), transposed: bits[((b*32+word)<<11)+row]
// seg1 (2048):  K -> Kf 32x32 A-frags (R6-verified layout)
// seg2 (1024):  V -> Vf 32x32 B-frags (R6-verified layout)
// seg3 (2048):  Q -> Qc bf16 row-major, pre-scaled by C1
__global__ __launch_bounds__(256) void prep_all(
    const void* __restrict__ M, const void* __restrict__ Kin,
    const void* __restrict__ Vin, const void* __restrict__ Qin,
    ull* __restrict__ bits, unsigned short* __restrict__ Kf,
    unsigned short* __restrict__ Vf, unsigned short* __restrict__ Qc) {
  __shared__ __align__(16) unsigned short T[64 * 72];
  const bool isb = detect_bf16(M);
  const unsigned bx = blockIdx.x;
  const int tid = threadIdx.x;

  if (bx < SEG0) {            // ---- mask bits, 8 elements per thread
    unsigned e0 = bx * 2048u + tid;
    #pragma unroll
    for (int j = 0; j < 8; ++j) {
      unsigned idx = e0 + (unsigned)j * 256u;
      bool on = isb ? (bf2f(((const unsigned short*)M)[idx]) > 0.5f)
                    : (((const float*)M)[idx] > 0.5f);
      ull bm = __ballot(on);
      if ((tid & 63) == 0) {
        unsigned c = idx & 2047u, r = (idx >> 11) & 2047u, bb = idx >> 22;
        bits[(((size_t)(bb * WPR + (c >> 6))) << 11) + r] = bm;
      }
    }
  } else if (bx < SEG0 + SEG1) {   // ---- Kf gather
    unsigned g = (bx - SEG0) * 256u + tid;
    unsigned lane = g & 63u, f = (g >> 6) & 7u, it = (g >> 9) & 31u, bh = g >> 14;
    unsigned t = f >> 2, dc = f & 3, hi = lane >> 5, l31 = lane & 31;
    size_t src = (size_t)bh * (S_LEN * D_DIM) +
                 (size_t)(it * 64 + t * 32 + l31) * D_DIM + dc * 16 + hi * 8;
    int4 out;
    if (isb) out = *(const int4*)((const unsigned short*)Kin + src);
    else     out = cvt_f8((const float*)Kin + src);
    *(int4*)&Kf[(size_t)g * 8] = out;
  } else if (bx < SEG0 + SEG1 + SEG2) {  // ---- Vf transpose via LDS
    unsigned idx = bx - (SEG0 + SEG1);
    unsigned bh = idx >> 5, it = idx & 31u;
    {
      int k = tid >> 2, d0 = (tid & 3) * 16;
      size_t src = (size_t)bh * (S_LEN * D_DIM) + (size_t)(it * 64 + k) * D_DIM + d0;
      int4 a, c;
      if (isb) {
        const unsigned short* s = (const unsigned short*)Vin + src;
        a = *(const int4*)s; c = *(const int4*)(s + 8);
      } else {
        const float* s = (const float*)Vin + src;
        a = cvt_f8(s); c = cvt_f8(s + 8);
      }
      *(int4*)&T[k * 72 + d0] = a;
      *(int4*)&T[k * 72 + d0 + 8] = c;
    }
    __syncthreads();
    #pragma unroll
    for (int h = 0; h < 2; ++h) {
      int c = tid + h * 256;
      int lane = c & 63, f = c >> 6;
      int t = f >> 2, kc = (f >> 1) & 1, dt = f & 1;
      int hi = lane >> 5, l31 = lane & 31;
      unsigned short v[8];
      #pragma unroll
      for (int j = 0; j < 8; ++j)
        v[j] = T[(t * 32 + kc * 16 + hi * 8 + j) * 72 + dt * 32 + l31];
      *(int4*)&Vf[(((size_t)(bh * 32 + it)) * 8 + f) * 512 + lane * 8] = *(int4*)v;
    }
  } else {                       // ---- Qc: row-major bf16, scaled by C1
    size_t i0 = ((size_t)(bx - (SEG0 + SEG1 + SEG2)) * 256 + tid) * 8;
    unsigned short v[8];
    if (isb) {
      *(int4*)v = *(const int4*)((const unsigned short*)Qin + i0);
      #pragma unroll
      for (int j = 0; j < 8; ++j) v[j] = f2bf(bf2f(v[j]) * C1);
    } else {
      const float* f = (const float*)Qin + i0;
      #pragma unroll
      for (int j = 0; j < 4; ++j)
        *((unsigned*)v + j) = packbf(f[2 * j] * C1, f[2 * j + 1] * C1);
    }
    *(int4*)&Qc[i0] = *(int4*)v;
  }
}

// ---------------- LDS-staged attention: block = 128 q-rows, shared k-sweep ----
// grid 512: id -> xcd=id&7, bh=xcd*4+(slot&3), qb=slot>>2 (slot=id>>3).
// Wave w owns q-rows [qb*128+w*32, +32); all 4 waves consume the same staged
// k-subtile (32 k-rows: 4 K frags + 4 V frags = 8KB), double-buffered.
__global__ __launch_bounds__(256, 4) void attn_fast(
    const unsigned short* __restrict__ Qc, const unsigned short* __restrict__ Kf,
    const unsigned short* __restrict__ Vf, const ull* __restrict__ bits,
    const void* __restrict__ maskp, void* __restrict__ Op) {
  __shared__ __align__(16) unsigned short Stg[2][8][512];  // [buf][0-3:K 4-7:V][1KB]
  __shared__ float Ls[4][32];                              // per-wave row-sums

  const bool isb = detect_bf16(maskp);
  const int tid  = threadIdx.x;
  const int wave = tid >> 6;
  const int lane = tid & 63;
  const int hi   = lane >> 5;
  const int l31  = lane & 31;
  const int id   = blockIdx.x;
  const int slot = id >> 3;
  const int bh   = (id & 7) * 4 + (slot & 3);   // XCD-affine: 4 bh per XCD
  const int qb   = slot >> 2;                   // 0..15
  const int qbase = qb * 128 + wave * 32;       // this wave's 32 q-rows
  const int b    = bh >> 4;
  const size_t base = (size_t)bh * S_LEN * D_DIM;
  const int xidx = ((lane ^ 32) & 63) * 4;      // ds_bpermute byte index

  // Q B-fragments: bf16 row-major, already scaled by C1
  bf16x8 qf[4];
  #pragma unroll
  for (int dc = 0; dc < 4; ++dc)
    qf[dc] = *(const bf16x8*)&Qc[base + (size_t)(qbase + l31) * D_DIM + dc * 16 + hi * 8];

  // Subtile ks (=it*2+t) K frags live at Kf + bh*131072 + ks*2048 (+dc*512),
  // contiguous 4KB; same for V. Wave w stages chunk w (K) and 4+w (V).
  const unsigned short* Ksrc = Kf + (size_t)bh * 131072 + (size_t)wave * 512 + lane * 8;
  const unsigned short* Vsrc = Vf + (size_t)bh * 131072 + (size_t)wave * 512 + lane * 8;
  const size_t bitbase = ((size_t)(b * WPR) << 11) + (size_t)(qbase + l31);

  f32x16 acc_o[2];   // [dt]: O[m=(reg&3)+8(reg>>2)+4hi][d=dt*32+l31]
  float ls0 = 0.f, ls1 = 0.f, ls2 = 0.f, ls3 = 0.f;
  #pragma unroll
  for (int r = 0; r < 16; ++r) { acc_o[0][r] = 0.f; acc_o[1][r] = 0.f; }

  // prologue: stage subtile 0 into buf 0
  gl_lds16(Ksrc, &Stg[0][wave][0]);
  gl_lds16(Vsrc, &Stg[0][4 + wave][0]);
  __syncthreads();   // drains vmcnt (compiler emits full waitcnt before barrier)

  ull wcur = 0;
  #pragma unroll 2
  for (int ks = 0; ks < 64; ++ks) {
    const int cur = ks & 1;
    // stage next subtile into the other buffer (flies under this compute)
    if (ks < 63) {
      gl_lds16(Ksrc + (size_t)(ks + 1) * 2048, &Stg[cur ^ 1][wave][0]);
      gl_lds16(Vsrc + (size_t)(ks + 1) * 2048, &Stg[cur ^ 1][4 + wave][0]);
    }
    if (!(ks & 1)) wcur = bits[bitbase + ((size_t)(ks >> 1) << 11)];

    // QK^T from staged K frags (conflict-free ds_read_b128)
    f32x16 sc;
    #pragma unroll
    for (int r = 0; r < 16; ++r) sc[r] = 0.f;
    #pragma unroll
    for (int dc = 0; dc < 4; ++dc) {
      bf16x8 kfr = *(const bf16x8*)&Stg[cur][dc][lane * 8];
      sc = mfma32(kfr, qf[dc], sc);
    }

    const unsigned wtv = (unsigned)((wcur >> (hi * 4)) >> (32 * (ks & 1)));

    float p[16];
    #pragma unroll
    for (int r = 0; r < 16; ++r) {
      float e = fexp2(sc[r]);
      unsigned bit = (wtv >> ((r & 3) + 8 * (r >> 2))) & 1u;
      p[r] = bit ? 0.0f : e;
    }
    ls0 += p[0] + p[4] + p[8]  + p[12];
    ls1 += p[1] + p[5] + p[9]  + p[13];
    ls2 += p[2] + p[6] + p[10] + p[14];
    ls3 += p[3] + p[7] + p[11] + p[15];

    #pragma unroll
    for (int kc = 0; kc < 2; ++kc) {
      unsigned pk0 = packbf(p[8 * kc + 0], p[8 * kc + 1]);
      unsigned pk1 = packbf(p[8 * kc + 2], p[8 * kc + 3]);
      unsigned pk2 = packbf(p[8 * kc + 4], p[8 * kc + 5]);
      unsigned pk3 = packbf(p[8 * kc + 6], p[8 * kc + 7]);
      uint4 d;
#if __has_builtin(__builtin_amdgcn_permlane32_swap)
      uint2v s02 = __builtin_amdgcn_permlane32_swap(pk0, pk2, false, false);
      uint2v s13 = __builtin_amdgcn_permlane32_swap(pk1, pk3, false, false);
      d.x = s02[0]; d.z = s02[1];
      d.y = s13[0]; d.w = s13[1];
#else
      unsigned x0 = (unsigned)__builtin_amdgcn_ds_bpermute(xidx, (int)pk0);
      unsigned x1 = (unsigned)__builtin_amdgcn_ds_bpermute(xidx, (int)pk1);
      unsigned x2 = (unsigned)__builtin_amdgcn_ds_bpermute(xidx, (int)pk2);
      unsigned x3 = (unsigned)__builtin_amdgcn_ds_bpermute(xidx, (int)pk3);
      d.x = hi ? x2 : pk0;
      d.y = hi ? x3 : pk1;
      d.z = hi ? pk2 : x0;
      d.w = hi ? pk3 : x1;
#endif
      bf16x8 pf = __builtin_bit_cast(bf16x8, d);
      #pragma unroll
      for (int dt = 0; dt < 2; ++dt) {
        bf16x8 vfr = *(const bf16x8*)&Stg[cur][4 + kc * 2 + dt][lane * 8];
        acc_o[dt] = mfma32(pf, vfr, acc_o[dt]);
      }
    }

    // one barrier per subtile: (a) next-tile stage landed (vmcnt drain),
    // (b) all waves done with buf[cur] before it's restaged next iter.
    __syncthreads();
  }

  // complete row-sum: add partner hi-half (both lanes end with the total)
  float lsum = (ls0 + ls1) + (ls2 + ls3);
  {
    int li = __builtin_bit_cast(int, lsum);
    float other = __builtin_bit_cast(float, __builtin_amdgcn_ds_bpermute(xidx, li));
    lsum += other;
  }
  if (hi == 0) Ls[wave][l31] = lsum;   // wave-private table, no barrier needed

  #pragma unroll
  for (int r = 0; r < 16; ++r) {
    int m = (r & 3) + 8 * (r >> 2) + 4 * hi;
    float inv = 1.0f / Ls[wave][m];
    float o0 = acc_o[0][r] * inv;
    float o1 = acc_o[1][r] * inv;
    size_t idx = base + (size_t)(qbase + m) * D_DIM + l31;
    if (isb) {
      ((unsigned short*)Op)[idx]      = f2bf(o0);
      ((unsigned short*)Op)[idx + 32] = f2bf(o1);
    } else {
      ((float*)Op)[idx]      = o0;
      ((float*)Op)[idx + 32] = o1;
    }
  }
}

// ---------------- no-workspace fallback (R2-proven structure) ----------------
__global__ __launch_bounds__(256, 2) void attn_fallback(
    const void* __restrict__ Qp, const void* __restrict__ Kp,
    const void* __restrict__ Vp, const void* __restrict__ maskp,
    void* __restrict__ Op) {
  __shared__ __align__(16) short QKlds[128 * 72];
  __shared__ __align__(16) short Vtlds[64 * 72];
  __shared__ __align__(16) short Plds2[128 * 72];

  const bool isb = detect_bf16(maskp);
  const int tid  = threadIdx.x;
  const int wave = tid >> 6;
  const int lane = tid & 63;
  const int l15  = lane & 15;
  const int quad = lane >> 4;
  const int q0   = blockIdx.x * 128;
  const int bh   = blockIdx.y;
  const int b    = bh >> 4;
  const size_t base = (size_t)bh * S_LEN * D_DIM;

  const short* Qs = (const short*)Qp; const float* Qf = (const float*)Qp;
  const short* Ks = (const short*)Kp; const float* Kf2 = (const float*)Kp;
  const short* Vs = (const short*)Vp; const float* Vf2 = (const float*)Vp;

  if (isb) {
    const short* Qg = Qs + base + (size_t)q0 * D_DIM;
    #pragma unroll
    for (int p = 0; p < 4; ++p) {
      int e = p * 2048 + tid * 8;
      *(int4*)&QKlds[(e >> 6) * 72 + (e & 63)] = *(const int4*)(Qg + e);
    }
  } else {
    const float* Qg = Qf + base + (size_t)q0 * D_DIM;
    #pragma unroll
    for (int p = 0; p < 4; ++p) {
      int e = p * 2048 + tid * 8;
      *(int4*)&QKlds[(e >> 6) * 72 + (e & 63)] = cvt_f8(Qg + e);
    }
  }
  __syncthreads();
  bf16x8 qf[2][2];
  #pragma unroll
  for (int mi = 0; mi < 2; ++mi)
    #pragma unroll
    for (int kt = 0; kt < 2; ++kt)
      qf[mi][kt] = *(const bf16x8*)&QKlds[(wave * 32 + mi * 16 + l15) * 72 + kt * 32 + quad * 8];
  __syncthreads();

  f32x4 acc_o[2][4];
  f32x4 acc_l[2];
  const f32x4 zero4 = {0.f, 0.f, 0.f, 0.f};
  #pragma unroll
  for (int mi = 0; mi < 2; ++mi) {
    acc_l[mi] = zero4;
    #pragma unroll
    for (int nt = 0; nt < 4; ++nt) acc_o[mi][nt] = zero4;
  }
  bf16x8 onesB;
  {
    short ov = (l15 == 0) ? (short)0x3F80 : (short)0;
    #pragma unroll
    for (int i = 0; i < 8; ++i) onesB[i] = ov;
  }

  for (int it = 0; it < NIT; ++it) {
    const int k0 = it * 64;
    if (isb) {
      const short* Kg = Ks + base + (size_t)k0 * D_DIM;
      #pragma unroll
      for (int p = 0; p < 2; ++p) {
        int e = p * 2048 + tid * 8;
        *(int4*)&QKlds[(e >> 6) * 72 + (e & 63)] = *(const int4*)(Kg + e);
      }
    } else {
      const float* Kg = Kf2 + base + (size_t)k0 * D_DIM;
      #pragma unroll
      for (int p = 0; p < 2; ++p) {
        int e = p * 2048 + tid * 8;
        *(int4*)&QKlds[(e >> 6) * 72 + (e & 63)] = cvt_f8(Kg + e);
      }
    }
    {
      const int r0 = (tid >> 3) * 2;
      const int d0 = (tid & 7) * 8;
      unsigned short as_[8], bs_[8];
      if (isb) {
        const short* Vg = Vs + base + (size_t)k0 * D_DIM;
        *(int4*)as_ = *(const int4*)(Vg + r0 * D_DIM + d0);
        *(int4*)bs_ = *(const int4*)(Vg + (r0 + 1) * D_DIM + d0);
      } else {
        const float* Vg = Vf2 + base + (size_t)k0 * D_DIM;
        *(int4*)as_ = cvt_f8(Vg + r0 * D_DIM + d0);
        *(int4*)bs_ = cvt_f8(Vg + (r0 + 1) * D_DIM + d0);
      }
      #pragma unroll
      for (int j = 0; j < 8; ++j) {
        int d = d0 + j;
        int blk = (r0 >> 3) ^ (d >> 3);
        unsigned pk = (unsigned)as_[j] | ((unsigned)bs_[j] << 16);
        *(unsigned*)&Vtlds[d * 72 + blk * 8 + (r0 & 7)] = pk;
      }
    }
    __syncthreads();

    f32x4 sc[2][4];
    #pragma unroll
    for (int mi = 0; mi < 2; ++mi)
      #pragma unroll
      for (int nt = 0; nt < 4; ++nt) sc[mi][nt] = zero4;
    #pragma unroll
    for (int nt = 0; nt < 4; ++nt) {
      bf16x8 kf0 = *(const bf16x8*)&QKlds[(nt * 16 + l15) * 72 + quad * 8];
      bf16x8 kf1 = *(const bf16x8*)&QKlds[(nt * 16 + l15) * 72 + 32 + quad * 8];
      #pragma unroll
      for (int mi = 0; mi < 2; ++mi) {
        sc[mi][nt] = mfma16(qf[mi][0], kf0, sc[mi][nt]);
        sc[mi][nt] = mfma16(qf[mi][1], kf1, sc[mi][nt]);
      }
    }

    #pragma unroll
    for (int mi = 0; mi < 2; ++mi) {
      #pragma unroll
      for (int nt = 0; nt < 4; ++nt) {
        #pragma unroll
        for (int reg = 0; reg < 4; ++reg) {
          int rg = q0 + wave * 32 + mi * 16 + quad * 4 + reg;
          size_t mix = (size_t)b * S_LEN * S_LEN + (size_t)rg * S_LEN + k0 + nt * 16 + l15;
          float mv = isb ? bf2f(((const unsigned short*)maskp)[mix])
                         : ((const float*)maskp)[mix];
          float y = sc[mi][nt][reg] * C1 - mv * C2;
          Plds2[(wave * 32 + mi * 16 + quad * 4 + reg) * 72 + nt * 16 + l15] =
              (short)f2bf(fexp2(y));
        }
      }
    }
    __syncthreads();

    #pragma unroll
    for (int kt = 0; kt < 2; ++kt) {
      bf16x8 pf[2];
      #pragma unroll
      for (int mi = 0; mi < 2; ++mi)
        pf[mi] = *(const bf16x8*)&Plds2[(wave * 32 + mi * 16 + l15) * 72 + kt * 32 + quad * 8];
      #pragma unroll
      for (int nt = 0; nt < 4; ++nt) {
        int d = nt * 16 + l15;
        int kb = (kt * 4 + quad) ^ (d >> 3);
        bf16x8 vf = *(const bf16x8*)&Vtlds[d * 72 + kb * 8];
        #pragma unroll
        for (int mi = 0; mi < 2; ++mi)
          acc_o[mi][nt] = mfma16(pf[mi], vf, acc_o[mi][nt]);
      }
      #pragma unroll
      for (int mi = 0; mi < 2; ++mi)
        acc_l[mi] = mfma16(pf[mi], onesB, acc_l[mi]);
    }
    __syncthreads();
  }

  #pragma unroll
  for (int mi = 0; mi < 2; ++mi) {
    #pragma unroll
    for (int reg = 0; reg < 4; ++reg) {
      float lv = __shfl(acc_l[mi][reg], lane & 48, 64);
      float inv = 1.0f / lv;
      #pragma unroll
      for (int nt = 0; nt < 4; ++nt) {
        float o = acc_o[mi][nt][reg] * inv;
        size_t idx = base + (size_t)(q0 + wave * 32 + mi * 16 + quad * 4 + reg) * D_DIM + nt * 16 + l15;
        if (isb) ((unsigned short*)Op)[idx] = f2bf(o);
        else     ((float*)Op)[idx] = o;
      }
    }
  }
}

extern "C" void kernel_launch(void* const* d_in, const int* in_sizes, int n_in,
                              void* d_out, int out_size, void* d_ws, size_t ws_size,
                              hipStream_t stream) {
  const void* Q = d_in[0];
  const void* K = d_in[1];
  const void* V = d_in[2];
  const void* M = d_in[3];

  dim3 block(256);
  const size_t bits_bytes = (size_t)2 * S_LEN * S_LEN / 8;          // 1 MB
  const size_t tens_bytes = (size_t)2 * 16 * S_LEN * D_DIM * 2;     // 8.4 MB bf16

  if (ws_size >= bits_bytes + 3 * tens_bytes) {
    char* ws = (char*)d_ws;
    ull* bits = (ull*)ws;
    unsigned short* Kf = (unsigned short*)(ws + bits_bytes);
    unsigned short* Vf = (unsigned short*)(ws + bits_bytes + tens_bytes);
    unsigned short* Qc = (unsigned short*)(ws + bits_bytes + 2 * tens_bytes);
    prep_all<<<dim3(SEG0 + SEG1 + SEG2 + SEG3), block, 0, stream>>>(
        M, K, V, Q, bits, Kf, Vf, Qc);
    attn_fast<<<dim3(512), block, 0, stream>>>(Qc, Kf, Vf, bits, M, d_out);
  } else {
    attn_fallback<<<dim3(S_LEN / 128, 32), block, 0, stream>>>(Q, K, V, M, d_out);
  }
}

// Round 4
// 165.966 us; speedup vs baseline: 1.2826x; 1.0397x over previous
//
#include <hip/hip_runtime.h>

// ScaleDotProductAttention: B=2,H=16,S=2048,D=64 (fp32 in/out; bf16-adaptive).
// R11: ILP pass on R10's LDS-staged structure. Grid=512 -> only 2 waves/SIMD,
// so the per-subtile serial chain (ds_read -> 4 chained QK MFMA -> exp ->
// pack -> 4 chained PV MFMA -> barrier) is latency-exposed. Change: 2 subtiles
// per barrier phase (32 barriers, 2x16KB buffers) computed as INDEPENDENT
// chains (scA/scB, parity-split accA/accB merged at end) -> ~2x ILP.
// launch_bounds(256,2): grid caps occupancy at 2 waves/SIMD anyway; avoids
// the R9 rematerialization failure mode at higher VGPR.

#define S_LEN 2048
#define D_DIM 64
#define WPR   32
#define NIT   32

typedef __attribute__((ext_vector_type(8)))  short bf16x8;
typedef __attribute__((ext_vector_type(4)))  float f32x4;
typedef __attribute__((ext_vector_type(16))) float f32x16;
typedef unsigned uint2v __attribute__((ext_vector_type(2)));
typedef unsigned long long ull;

__device__ __forceinline__ f32x16 mfma32(bf16x8 a, bf16x8 b, f32x16 c) {
  return __builtin_amdgcn_mfma_f32_32x32x16_bf16(a, b, c, 0, 0, 0);
}
__device__ __forceinline__ f32x4 mfma16(bf16x8 a, bf16x8 b, f32x4 c) {
  return __builtin_amdgcn_mfma_f32_16x16x32_bf16(a, b, c, 0, 0, 0);
}
__device__ __forceinline__ unsigned short f2bf(float f) {
  unsigned u = __builtin_bit_cast(unsigned, f);
  unsigned r = u + 0x7FFFu + ((u >> 16) & 1u);
  return (unsigned short)(r >> 16);
}
__device__ __forceinline__ float bf2f(unsigned short s) {
  unsigned u = ((unsigned)s) << 16;
  return __builtin_bit_cast(float, u);
}
__device__ __forceinline__ unsigned packbf(float a, float b) {
  // gfx950: v_cvt_pk_bf16_f32 (RNE), no clang builtin -> inline asm (T12).
  unsigned r;
  asm("v_cvt_pk_bf16_f32 %0, %1, %2" : "=v"(r) : "v"(a), "v"(b));
  return r;
}
__device__ __forceinline__ float fexp2(float x) {
#if __has_builtin(__builtin_amdgcn_exp2f)
  return __builtin_amdgcn_exp2f(x);
#else
  return exp2f(x);
#endif
}
__device__ __forceinline__ bool detect_bf16(const void* maskp) {
  const unsigned short* s = (const unsigned short*)maskp;
  unsigned short v = s[2 * (threadIdx.x & 63)];
  return __ballot(v == (unsigned short)0x3F80) != 0ull;
}
__device__ __forceinline__ int4 cvt_f8(const float* p) {
  float4 f0 = *(const float4*)p;
  float4 f1 = *(const float4*)(p + 4);
  int4 r;
  r.x = (int)packbf(f0.x, f0.y);
  r.y = (int)packbf(f0.z, f0.w);
  r.z = (int)packbf(f1.x, f1.y);
  r.w = (int)packbf(f1.z, f1.w);
  return r;
}
// Async 16B/lane global->LDS. g is PER-LANE src (base + lane*16B); l is the
// wave-uniform LDS base (HW writes lane i at l + i*16).
__device__ __forceinline__ void gl_lds16(const unsigned short* g, unsigned short* l) {
#if __has_builtin(__builtin_amdgcn_global_load_lds)
  __builtin_amdgcn_global_load_lds(
      (const __attribute__((address_space(1))) unsigned int*)g,
      (__attribute__((address_space(3))) unsigned int*)l, 16, 0, 0);
#else
  *(int4*)((char*)l + (threadIdx.x & 63) * 16) = *(const int4*)g;
#endif
}

#define C1 0.18033688011112042f     /* (1/sqrt(64))*log2(e) */
#define C2 1.4426950408889634e9f

#define SEG0 4096u
#define SEG1 2048u
#define SEG2 1024u
#define SEG3 2048u

// ---------------- unified prepass ----------------
// seg0 (4096):  mask -> bits (8 elems/thread), transposed: bits[((b*32+word)<<11)+row]
// seg1 (2048):  K -> Kf 32x32 A-frags (R6-verified layout)
// seg2 (1024):  V -> Vf 32x32 B-frags (R6-verified layout)
// seg3 (2048):  Q -> Qc bf16 row-major, pre-scaled by C1
__global__ __launch_bounds__(256) void prep_all(
    const void* __restrict__ M, const void* __restrict__ Kin,
    const void* __restrict__ Vin, const void* __restrict__ Qin,
    ull* __restrict__ bits, unsigned short* __restrict__ Kf,
    unsigned short* __restrict__ Vf, unsigned short* __restrict__ Qc) {
  __shared__ __align__(16) unsigned short T[64 * 72];
  const bool isb = detect_bf16(M);
  const unsigned bx = blockIdx.x;
  const int tid = threadIdx.x;

  if (bx < SEG0) {            // ---- mask bits, 8 elements per thread
    unsigned e0 = bx * 2048u + tid;
    #pragma unroll
    for (int j = 0; j < 8; ++j) {
      unsigned idx = e0 + (unsigned)j * 256u;
      bool on = isb ? (bf2f(((const unsigned short*)M)[idx]) > 0.5f)
                    : (((const float*)M)[idx] > 0.5f);
      ull bm = __ballot(on);
      if ((tid & 63) == 0) {
        unsigned c = idx & 2047u, r = (idx >> 11) & 2047u, bb = idx >> 22;
        bits[(((size_t)(bb * WPR + (c >> 6))) << 11) + r] = bm;
      }
    }
  } else if (bx < SEG0 + SEG1) {   // ---- Kf gather
    unsigned g = (bx - SEG0) * 256u + tid;
    unsigned lane = g & 63u, f = (g >> 6) & 7u, it = (g >> 9) & 31u, bh = g >> 14;
    unsigned t = f >> 2, dc = f & 3, hi = lane >> 5, l31 = lane & 31;
    size_t src = (size_t)bh * (S_LEN * D_DIM) +
                 (size_t)(it * 64 + t * 32 + l31) * D_DIM + dc * 16 + hi * 8;
    int4 out;
    if (isb) out = *(const int4*)((const unsigned short*)Kin + src);
    else     out = cvt_f8((const float*)Kin + src);
    *(int4*)&Kf[(size_t)g * 8] = out;
  } else if (bx < SEG0 + SEG1 + SEG2) {  // ---- Vf transpose via LDS
    unsigned idx = bx - (SEG0 + SEG1);
    unsigned bh = idx >> 5, it = idx & 31u;
    {
      int k = tid >> 2, d0 = (tid & 3) * 16;
      size_t src = (size_t)bh * (S_LEN * D_DIM) + (size_t)(it * 64 + k) * D_DIM + d0;
      int4 a, c;
      if (isb) {
        const unsigned short* s = (const unsigned short*)Vin + src;
        a = *(const int4*)s; c = *(const int4*)(s + 8);
      } else {
        const float* s = (const float*)Vin + src;
        a = cvt_f8(s); c = cvt_f8(s + 8);
      }
      *(int4*)&T[k * 72 + d0] = a;
      *(int4*)&T[k * 72 + d0 + 8] = c;
    }
    __syncthreads();
    #pragma unroll
    for (int h = 0; h < 2; ++h) {
      int c = tid + h * 256;
      int lane = c & 63, f = c >> 6;
      int t = f >> 2, kc = (f >> 1) & 1, dt = f & 1;
      int hi = lane >> 5, l31 = lane & 31;
      unsigned short v[8];
      #pragma unroll
      for (int j = 0; j < 8; ++j)
        v[j] = T[(t * 32 + kc * 16 + hi * 8 + j) * 72 + dt * 32 + l31];
      *(int4*)&Vf[(((size_t)(bh * 32 + it)) * 8 + f) * 512 + lane * 8] = *(int4*)v;
    }
  } else {                       // ---- Qc: row-major bf16, scaled by C1
    size_t i0 = ((size_t)(bx - (SEG0 + SEG1 + SEG2)) * 256 + tid) * 8;
    unsigned short v[8];
    if (isb) {
      *(int4*)v = *(const int4*)((const unsigned short*)Qin + i0);
      #pragma unroll
      for (int j = 0; j < 8; ++j) v[j] = f2bf(bf2f(v[j]) * C1);
    } else {
      const float* f = (const float*)Qin + i0;
      #pragma unroll
      for (int j = 0; j < 4; ++j)
        *((unsigned*)v + j) = packbf(f[2 * j] * C1, f[2 * j + 1] * C1);
    }
    *(int4*)&Qc[i0] = *(int4*)v;
  }
}

// ---------------- LDS-staged attention: block = 128 q-rows, shared k-sweep ----
// grid 512: id -> xcd=id&7, bh=xcd*4+(slot&3), qb=slot>>2 (slot=id>>3).
// Wave w owns q-rows [qb*128+w*32, +32). Per phase (32 total): all 4 waves
// consume the SAME two staged k-subtiles (2x(4K+4V frags)=16KB) as two
// independent compute chains; next phase staged under current compute.
__global__ __launch_bounds__(256, 2) void attn_fast(
    const unsigned short* __restrict__ Qc, const unsigned short* __restrict__ Kf,
    const unsigned short* __restrict__ Vf, const ull* __restrict__ bits,
    const void* __restrict__ maskp, void* __restrict__ Op) {
  __shared__ __align__(16) unsigned short Stg[2][2][8][512]; // [buf][sub][frag][1KB]
  __shared__ float Ls[4][32];                                // per-wave row-sums

  const bool isb = detect_bf16(maskp);
  const int tid  = threadIdx.x;
  const int wave = tid >> 6;
  const int lane = tid & 63;
  const int hi   = lane >> 5;
  const int l31  = lane & 31;
  const int id   = blockIdx.x;
  const int slot = id >> 3;
  const int bh   = (id & 7) * 4 + (slot & 3);   // XCD-affine: 4 bh per XCD
  const int qb   = slot >> 2;                   // 0..15
  const int qbase = qb * 128 + wave * 32;       // this wave's 32 q-rows
  const int b    = bh >> 4;
  const size_t base = (size_t)bh * S_LEN * D_DIM;
  const int xidx = ((lane ^ 32) & 63) * 4;      // ds_bpermute byte index

  // Q B-fragments: bf16 row-major, already scaled by C1
  bf16x8 qf[4];
  #pragma unroll
  for (int dc = 0; dc < 4; ++dc)
    qf[dc] = *(const bf16x8*)&Qc[base + (size_t)(qbase + l31) * D_DIM + dc * 16 + hi * 8];

  // Subtile ks frags at Kf + bh*131072 + ks*2048 (+frag*512), ushort units.
  // Wave w stages frag w (K) and frag 4+w (V) of each subtile.
  const unsigned short* Ksrc = Kf + (size_t)bh * 131072 + (size_t)wave * 512 + lane * 8;
  const unsigned short* Vsrc = Vf + (size_t)bh * 131072 + (size_t)wave * 512 + lane * 8;
  const size_t bitbase = ((size_t)(b * WPR) << 11) + (size_t)(qbase + l31);

  f32x16 accA[2], accB[2];   // parity-split: [dt] O[m=(reg&3)+8(reg>>2)+4hi][d=dt*32+l31]
  float ls0 = 0.f, ls1 = 0.f, ls2 = 0.f, ls3 = 0.f;
  #pragma unroll
  for (int r = 0; r < 16; ++r) {
    accA[0][r] = 0.f; accA[1][r] = 0.f;
    accB[0][r] = 0.f; accB[1][r] = 0.f;
  }

  // prologue: stage phase 0 (subtiles 0,1) into buf 0
  #pragma unroll
  for (int s = 0; s < 2; ++s) {
    gl_lds16(Ksrc + (size_t)s * 2048, &Stg[0][s][wave][0]);
    gl_lds16(Vsrc + (size_t)s * 2048, &Stg[0][s][4 + wave][0]);
  }
  ull wcur = bits[bitbase];
  __syncthreads();   // drains vmcnt (compiler emits full waitcnt before barrier)

  #pragma unroll 2
  for (int f = 0; f < 32; ++f) {
    const int cur = f & 1;
    // stage next phase's 2 subtiles into the other buffer (fly under compute)
    if (f < 31) {
      #pragma unroll
      for (int s = 0; s < 2; ++s) {
        const size_t so = (size_t)(2 * (f + 1) + s) * 2048;
        gl_lds16(Ksrc + so, &Stg[cur ^ 1][s][wave][0]);
        gl_lds16(Vsrc + so, &Stg[cur ^ 1][s][4 + wave][0]);
      }
    }
    ull wnext = (f < 31) ? bits[bitbase + ((size_t)(f + 1) << 11)] : 0ull;

    // --- two independent QK^T chains from staged K frags ---
    bf16x8 ka[4], kb[4];
    #pragma unroll
    for (int dc = 0; dc < 4; ++dc) {
      ka[dc] = *(const bf16x8*)&Stg[cur][0][dc][lane * 8];
      kb[dc] = *(const bf16x8*)&Stg[cur][1][dc][lane * 8];
    }
    f32x16 scA, scB;
    #pragma unroll
    for (int r = 0; r < 16; ++r) { scA[r] = 0.f; scB[r] = 0.f; }
    #pragma unroll
    for (int dc = 0; dc < 4; ++dc) {
      scA = mfma32(ka[dc], qf[dc], scA);
      scB = mfma32(kb[dc], qf[dc], scB);
    }

    const ull wsh = wcur >> (hi * 4);
    const unsigned wtvA = (unsigned)wsh;
    const unsigned wtvB = (unsigned)(wsh >> 32);

    float pA[16], pB[16];
    #pragma unroll
    for (int r = 0; r < 16; ++r) {
      const int bi = (r & 3) + 8 * (r >> 2);
      float eA = fexp2(scA[r]);
      float eB = fexp2(scB[r]);
      pA[r] = ((wtvA >> bi) & 1u) ? 0.0f : eA;
      pB[r] = ((wtvB >> bi) & 1u) ? 0.0f : eB;
    }
    ls0 += (pA[0] + pA[4] + pA[8]  + pA[12]) + (pB[0] + pB[4] + pB[8]  + pB[12]);
    ls1 += (pA[1] + pA[5] + pA[9]  + pA[13]) + (pB[1] + pB[5] + pB[9]  + pB[13]);
    ls2 += (pA[2] + pA[6] + pA[10] + pA[14]) + (pB[2] + pB[6] + pB[10] + pB[14]);
    ls3 += (pA[3] + pA[7] + pA[11] + pA[15]) + (pB[3] + pB[7] + pB[11] + pB[15]);

    // --- pack + half-swap + PV, subtile A -> accA, subtile B -> accB ---
    #pragma unroll
    for (int kc = 0; kc < 2; ++kc) {
      unsigned a0 = packbf(pA[8 * kc + 0], pA[8 * kc + 1]);
      unsigned a1 = packbf(pA[8 * kc + 2], pA[8 * kc + 3]);
      unsigned a2 = packbf(pA[8 * kc + 4], pA[8 * kc + 5]);
      unsigned a3 = packbf(pA[8 * kc + 6], pA[8 * kc + 7]);
      unsigned b0 = packbf(pB[8 * kc + 0], pB[8 * kc + 1]);
      unsigned b1 = packbf(pB[8 * kc + 2], pB[8 * kc + 3]);
      unsigned b2 = packbf(pB[8 * kc + 4], pB[8 * kc + 5]);
      unsigned b3 = packbf(pB[8 * kc + 6], pB[8 * kc + 7]);
      uint4 dA, dB;
#if __has_builtin(__builtin_amdgcn_permlane32_swap)
      uint2v sA02 = __builtin_amdgcn_permlane32_swap(a0, a2, false, false);
      uint2v sA13 = __builtin_amdgcn_permlane32_swap(a1, a3, false, false);
      dA.x = sA02[0]; dA.z = sA02[1];
      dA.y = sA13[0]; dA.w = sA13[1];
      uint2v sB02 = __builtin_amdgcn_permlane32_swap(b0, b2, false, false);
      uint2v sB13 = __builtin_amdgcn_permlane32_swap(b1, b3, false, false);
      dB.x = sB02[0]; dB.z = sB02[1];
      dB.y = sB13[0]; dB.w = sB13[1];
#else
      unsigned xa0 = (unsigned)__builtin_amdgcn_ds_bpermute(xidx, (int)a0);
      unsigned xa1 = (unsigned)__builtin_amdgcn_ds_bpermute(xidx, (int)a1);
      unsigned xa2 = (unsigned)__builtin_amdgcn_ds_bpermute(xidx, (int)a2);
      unsigned xa3 = (unsigned)__builtin_amdgcn_ds_bpermute(xidx, (int)a3);
      dA.x = hi ? xa2 : a0;  dA.y = hi ? xa3 : a1;
      dA.z = hi ? a2 : xa0;  dA.w = hi ? a3 : xa1;
      unsigned xb0 = (unsigned)__builtin_amdgcn_ds_bpermute(xidx, (int)b0);
      unsigned xb1 = (unsigned)__builtin_amdgcn_ds_bpermute(xidx, (int)b1);
      unsigned xb2 = (unsigned)__builtin_amdgcn_ds_bpermute(xidx, (int)b2);
      unsigned xb3 = (unsigned)__builtin_amdgcn_ds_bpermute(xidx, (int)b3);
      dB.x = hi ? xb2 : b0;  dB.y = hi ? xb3 : b1;
      dB.z = hi ? b2 : xb0;  dB.w = hi ? b3 : xb1;
#endif
      bf16x8 pfA = __builtin_bit_cast(bf16x8, dA);
      bf16x8 pfB = __builtin_bit_cast(bf16x8, dB);
      #pragma unroll
      for (int dt = 0; dt < 2; ++dt) {
        bf16x8 vfA = *(const bf16x8*)&Stg[cur][0][4 + kc * 2 + dt][lane * 8];
        bf16x8 vfB = *(const bf16x8*)&Stg[cur][1][4 + kc * 2 + dt][lane * 8];
        accA[dt] = mfma32(pfA, vfA, accA[dt]);
        accB[dt] = mfma32(pfB, vfB, accB[dt]);
      }
    }

    // one barrier per phase: (a) next-phase stage landed (vmcnt drain),
    // (b) all waves done with buf[cur] before it's restaged next phase.
    __syncthreads();
    wcur = wnext;
  }

  // merge parity accumulators
  f32x16 acc_o[2];
  #pragma unroll
  for (int r = 0; r < 16; ++r) {
    acc_o[0][r] = accA[0][r] + accB[0][r];
    acc_o[1][r] = accA[1][r] + accB[1][r];
  }

  // complete row-sum: add partner hi-half (both lanes end with the total)
  float lsum = (ls0 + ls1) + (ls2 + ls3);
  {
    int li = __builtin_bit_cast(int, lsum);
    float other = __builtin_bit_cast(float, __builtin_amdgcn_ds_bpermute(xidx, li));
    lsum += other;
  }
  if (hi == 0) Ls[wave][l31] = lsum;   // wave-private table, no barrier needed

  #pragma unroll
  for (int r = 0; r < 16; ++r) {
    int m = (r & 3) + 8 * (r >> 2) + 4 * hi;
    float inv = 1.0f / Ls[wave][m];
    float o0 = acc_o[0][r] * inv;
    float o1 = acc_o[1][r] * inv;
    size_t idx = base + (size_t)(qbase + m) * D_DIM + l31;
    if (isb) {
      ((unsigned short*)Op)[idx]      = f2bf(o0);
      ((unsigned short*)Op)[idx + 32] = f2bf(o1);
    } else {
      ((float*)Op)[idx]      = o0;
      ((float*)Op)[idx + 32] = o1;
    }
  }
}

// ---------------- no-workspace fallback (R2-proven structure) ----------------
__global__ __launch_bounds__(256, 2) void attn_fallback(
    const void* __restrict__ Qp, const void* __restrict__ Kp,
    const void* __restrict__ Vp, const void* __restrict__ maskp,
    void* __restrict__ Op) {
  __shared__ __align__(16) short QKlds[128 * 72];
  __shared__ __align__(16) short Vtlds[64 * 72];
  __shared__ __align__(16) short Plds2[128 * 72];

  const bool isb = detect_bf16(maskp);
  const int tid  = threadIdx.x;
  const int wave = tid >> 6;
  const int lane = tid & 63;
  const int l15  = lane & 15;
  const int quad = lane >> 4;
  const int q0   = blockIdx.x * 128;
  const int bh   = blockIdx.y;
  const int b    = bh >> 4;
  const size_t base = (size_t)bh * S_LEN * D_DIM;

  const short* Qs = (const short*)Qp; const float* Qf = (const float*)Qp;
  const short* Ks = (const short*)Kp; const float* Kf2 = (const float*)Kp;
  const short* Vs = (const short*)Vp; const float* Vf2 = (const float*)Vp;

  if (isb) {
    const short* Qg = Qs + base + (size_t)q0 * D_DIM;
    #pragma unroll
    for (int p = 0; p < 4; ++p) {
      int e = p * 2048 + tid * 8;
      *(int4*)&QKlds[(e >> 6) * 72 + (e & 63)] = *(const int4*)(Qg + e);
    }
  } else {
    const float* Qg = Qf + base + (size_t)q0 * D_DIM;
    #pragma unroll
    for (int p = 0; p < 4; ++p) {
      int e = p * 2048 + tid * 8;
      *(int4*)&QKlds[(e >> 6) * 72 + (e & 63)] = cvt_f8(Qg + e);
    }
  }
  __syncthreads();
  bf16x8 qf[2][2];
  #pragma unroll
  for (int mi = 0; mi < 2; ++mi)
    #pragma unroll
    for (int kt = 0; kt < 2; ++kt)
      qf[mi][kt] = *(const bf16x8*)&QKlds[(wave * 32 + mi * 16 + l15) * 72 + kt * 32 + quad * 8];
  __syncthreads();

  f32x4 acc_o[2][4];
  f32x4 acc_l[2];
  const f32x4 zero4 = {0.f, 0.f, 0.f, 0.f};
  #pragma unroll
  for (int mi = 0; mi < 2; ++mi) {
    acc_l[mi] = zero4;
    #pragma unroll
    for (int nt = 0; nt < 4; ++nt) acc_o[mi][nt] = zero4;
  }
  bf16x8 onesB;
  {
    short ov = (l15 == 0) ? (short)0x3F80 : (short)0;
    #pragma unroll
    for (int i = 0; i < 8; ++i) onesB[i] = ov;
  }

  for (int it = 0; it < NIT; ++it) {
    const int k0 = it * 64;
    if (isb) {
      const short* Kg = Ks + base + (size_t)k0 * D_DIM;
      #pragma unroll
      for (int p = 0; p < 2; ++p) {
        int e = p * 2048 + tid * 8;
        *(int4*)&QKlds[(e >> 6) * 72 + (e & 63)] = *(const int4*)(Kg + e);
      }
    } else {
      const float* Kg = Kf2 + base + (size_t)k0 * D_DIM;
      #pragma unroll
      for (int p = 0; p < 2; ++p) {
        int e = p * 2048 + tid * 8;
        *(int4*)&QKlds[(e >> 6) * 72 + (e & 63)] = cvt_f8(Kg + e);
      }
    }
    {
      const int r0 = (tid >> 3) * 2;
      const int d0 = (tid & 7) * 8;
      unsigned short as_[8], bs_[8];
      if (isb) {
        const short* Vg = Vs + base + (size_t)k0 * D_DIM;
        *(int4*)as_ = *(const int4*)(Vg + r0 * D_DIM + d0);
        *(int4*)bs_ = *(const int4*)(Vg + (r0 + 1) * D_DIM + d0);
      } else {
        const float* Vg = Vf2 + base + (size_t)k0 * D_DIM;
        *(int4*)as_ = cvt_f8(Vg + r0 * D_DIM + d0);
        *(int4*)bs_ = cvt_f8(Vg + (r0 + 1) * D_DIM + d0);
      }
      #pragma unroll
      for (int j = 0; j < 8; ++j) {
        int d = d0 + j;
        int blk = (r0 >> 3) ^ (d >> 3);
        unsigned pk = (unsigned)as_[j] | ((unsigned)bs_[j] << 16);
        *(unsigned*)&Vtlds[d * 72 + blk * 8 + (r0 & 7)] = pk;
      }
    }
    __syncthreads();

    f32x4 sc[2][4];
    #pragma unroll
    for (int mi = 0; mi < 2; ++mi)
      #pragma unroll
      for (int nt = 0; nt < 4; ++nt) sc[mi][nt] = zero4;
    #pragma unroll
    for (int nt = 0; nt < 4; ++nt) {
      bf16x8 kf0 = *(const bf16x8*)&QKlds[(nt * 16 + l15) * 72 + quad * 8];
      bf16x8 kf1 = *(const bf16x8*)&QKlds[(nt * 16 + l15) * 72 + 32 + quad * 8];
      #pragma unroll
      for (int mi = 0; mi < 2; ++mi) {
        sc[mi][nt] = mfma16(qf[mi][0], kf0, sc[mi][nt]);
        sc[mi][nt] = mfma16(qf[mi][1], kf1, sc[mi][nt]);
      }
    }

    #pragma unroll
    for (int mi = 0; mi < 2; ++mi) {
      #pragma unroll
      for (int nt = 0; nt < 4; ++nt) {
        #pragma unroll
        for (int reg = 0; reg < 4; ++reg) {
          int rg = q0 + wave * 32 + mi * 16 + quad * 4 + reg;
          size_t mix = (size_t)b * S_LEN * S_LEN + (size_t)rg * S_LEN + k0 + nt * 16 + l15;
          float mv = isb ? bf2f(((const unsigned short*)maskp)[mix])
                         : ((const float*)maskp)[mix];
          float y = sc[mi][nt][reg] * C1 - mv * C2;
          Plds2[(wave * 32 + mi * 16 + quad * 4 + reg) * 72 + nt * 16 + l15] =
              (short)f2bf(fexp2(y));
        }
      }
    }
    __syncthreads();

    #pragma unroll
    for (int kt = 0; kt < 2; ++kt) {
      bf16x8 pf[2];
      #pragma unroll
      for (int mi = 0; mi < 2; ++mi)
        pf[mi] = *(const bf16x8*)&Plds2[(wave * 32 + mi * 16 + l15) * 72 + kt * 32 + quad * 8];
      #pragma unroll
      for (int nt = 0; nt < 4; ++nt) {
        int d = nt * 16 + l15;
        int kb = (kt * 4 + quad) ^ (d >> 3);
        bf16x8 vf = *(const bf16x8*)&Vtlds[d * 72 + kb * 8];
        #pragma unroll
        for (int mi = 0; mi < 2; ++mi)
          acc_o[mi][nt] = mfma16(pf[mi], vf, acc_o[mi][nt]);
      }
      #pragma unroll
      for (int mi = 0; mi < 2; ++mi)
        acc_l[mi] = mfma16(pf[mi], onesB, acc_l[mi]);
    }
    __syncthreads();
  }

  #pragma unroll
  for (int mi = 0; mi < 2; ++mi) {
    #pragma unroll
    for (int reg = 0; reg < 4; ++reg) {
      float lv = __shfl(acc_l[mi][reg], lane & 48, 64);
      float inv = 1.0f / lv;
      #pragma unroll
      for (int nt = 0; nt < 4; ++nt) {
        float o = acc_o[mi][nt][reg] * inv;
        size_t idx = base + (size_t)(q0 + wave * 32 + mi * 16 + quad * 4 + reg) * D_DIM + nt * 16 + l15;
        if (isb) ((unsigned short*)Op)[idx] = f2bf(o);
        else     ((float*)Op)[idx] = o;
      }
    }
  }
}

extern "C" void kernel_launch(void* const* d_in, const int* in_sizes, int n_in,
                              void* d_out, int out_size, void* d_ws, size_t ws_size,
                              hipStream_t stream) {
  const void* Q = d_in[0];
  const void* K = d_in[1];
  const void* V = d_in[2];
  const void* M = d_in[3];

  dim3 block(256);
  const size_t bits_bytes = (size_t)2 * S_LEN * S_LEN / 8;          // 1 MB
  const size_t tens_bytes = (size_t)2 * 16 * S_LEN * D_DIM * 2;     // 8.4 MB bf16

  if (ws_size >= bits_bytes + 3 * tens_bytes) {
    char* ws = (char*)d_ws;
    ull* bits = (ull*)ws;
    unsigned short* Kf = (unsigned short*)(ws + bits_bytes);
    unsigned short* Vf = (unsigned short*)(ws + bits_bytes + tens_bytes);
    unsigned short* Qc = (unsigned short*)(ws + bits_bytes + 2 * tens_bytes);
    prep_all<<<dim3(SEG0 + SEG1 + SEG2 + SEG3), block, 0, stream>>>(
        M, K, V, Q, bits, Kf, Vf, Qc);
    attn_fast<<<dim3(512), block, 0, stream>>>(Qc, Kf, Vf, bits, M, d_out);
  } else {
    attn_fallback<<<dim3(S_LEN / 128, 32), block, 0, stream>>>(Q, K, V, M, d_out);
  }
}